// Round 5
// baseline (186.594 us; speedup 1.0000x reference)
//
#include <hip/hip_runtime.h>
#include <hip/hip_bf16.h>

// StreamingConv == GEMM: C[b,o] = sum_k A[b,k]*W[o,k]; A[256][16384], W[1024][16384] f32.
// R5: traffic model: bytes = W(64) + A(16.8*Nnb) + ws(SKb partial slices, bf16).
// R4 was (Nnb=4,SKb=64) = 195 MB -> 34us. Now (Nnb=2,SKb=64) = 163 MB, 128 blocks.
// BN=512 forces bf16-in-LDS (reg-stage + cvt + XOR-swizzled ds_write), 1024-thread
// blocks (16 waves), 96 KB LDS double-buffer, one barrier/iter, permuted-column
// bf16 partial slices (coalesced short8 epilogue), reduce kernel inverts the perm.

#define CO    1024
#define KTOT  16384
#define BM    256
#define BN    512
#define NB    2                   // n-blocks
#define SKB   64                  // split-K blocks (= partial slices)
#define KC    (KTOT / SKB)        // 256
#define BK    32                  // bf16 k-step in LDS; row = 64 B = 4 x 16B groups
#define KITERS (KC / BK)          // 8
#define SLICE_ELEMS (BM * CO)     // 262144 per slice (both n-halves share a slice)

typedef __attribute__((ext_vector_type(8))) short short8;
typedef __attribute__((ext_vector_type(4))) float f32x4;

__device__ __forceinline__ short f2bf(float f) {
    union { __bf16 h; unsigned short u; } c; c.h = (__bf16)f; return (short)c.u;
}

__device__ __forceinline__ short8 pack8(f32x4 a, f32x4 b) {
    short8 r;
    r[0] = f2bf(a[0]); r[1] = f2bf(a[1]); r[2] = f2bf(a[2]); r[3] = f2bf(a[3]);
    r[4] = f2bf(b[0]); r[5] = f2bf(b[1]); r[6] = f2bf(b[2]); r[7] = f2bf(b[3]);
    return r;
}

// swizzle: physical 16B-group = logical_group ^ fswz(row); max 2-way bank alias
__device__ __forceinline__ int fswz(int r) { return (r ^ (r >> 2)) & 3; }

template <bool USE_WS>
__global__ __launch_bounds__(1024, 2)
void sconv_gemm_v5(const float* __restrict__ A, const float* __restrict__ W,
                   float* __restrict__ out, unsigned short* __restrict__ wsb) {
    __shared__ __align__(16) unsigned short lA[2][BM * BK];   // 2 x 16 KB
    __shared__ __align__(16) unsigned short lB[2][BN * BK];   // 2 x 32 KB

    const int tid  = threadIdx.x;
    const int wid  = tid >> 6;
    const int lane = tid & 63;
    const int bn = blockIdx.x * BN;          // 0 / 512
    const int kb = blockIdx.y;               // 0..63
    const int k0 = kb * KC;

    // ---- staging decomposition (per thread per iter: 6 f32x4 loads -> 3 ds_write_b128)
    // A: 256 rows x 4 groups = 1024 slots (1/thread); B: 512 x 4 = 2048 (2/thread)
    const int rA = tid >> 2, gA = tid & 3;
    const int rB = tid >> 2, gB = tid & 3;           // second B slot: row rB+256, same g
    const int wA  = rA * BK + (gA ^ fswz(rA)) * 8;   // ushort index, 16B-aligned
    const int wB0 = rB * BK + (gB ^ fswz(rB)) * 8;
    const int wB1 = wB0 + 256 * BK;                  // fswz(r+256)==fswz(r)

    const float* Ag  = A + (size_t)rA * KTOT + k0 + gA * 8;
    const float* Bg0 = W + (size_t)(bn + rB) * KTOT + k0 + gB * 8;
    const float* Bg1 = Bg0 + (size_t)256 * KTOT;

    // ---- wave -> 64M x 128N output sub-tile (4x4 wave grid over 256x512)
    const int wm = (wid >> 2) * 64;
    const int wn = (wid & 3) * 128;
    const int q  = lane >> 4;           // k-quarter
    const int fr = lane & 15;           // fragment row

    // frag LDS offsets are loop-invariant (only the buffer alternates)
    int offA[4], offB[8];
    #pragma unroll
    for (int mi = 0; mi < 4; ++mi) {
        int r = wm + mi * 16 + fr;
        offA[mi] = r * BK + ((q ^ fswz(r)) * 8);
    }
    #pragma unroll
    for (int ni = 0; ni < 8; ++ni) {
        int r = wn + ni * 16 + fr;
        offB[ni] = r * BK + ((q ^ fswz(r)) * 8);
    }

    f32x4 acc[4][8] = {};

    // prologue: tile 0 -> regs -> cvt -> LDS buf0
    {
        f32x4 a0 = *(const f32x4*)(Ag);
        f32x4 a1 = *(const f32x4*)(Ag + 4);
        f32x4 b00 = *(const f32x4*)(Bg0);
        f32x4 b01 = *(const f32x4*)(Bg0 + 4);
        f32x4 b10 = *(const f32x4*)(Bg1);
        f32x4 b11 = *(const f32x4*)(Bg1 + 4);
        *(short8*)&lA[0][wA]  = pack8(a0, a1);
        *(short8*)&lB[0][wB0] = pack8(b00, b01);
        *(short8*)&lB[0][wB1] = pack8(b10, b11);
    }
    __syncthreads();

    #pragma unroll
    for (int t = 0; t < KITERS; ++t) {
        // issue next tile's global loads BEFORE the MFMAs (they fly over compute)
        f32x4 a0, a1, b00, b01, b10, b11;
        if (t + 1 < KITERS) {
            const int o = (t + 1) * BK;
            a0  = *(const f32x4*)(Ag + o);
            a1  = *(const f32x4*)(Ag + o + 4);
            b00 = *(const f32x4*)(Bg0 + o);
            b01 = *(const f32x4*)(Bg0 + o + 4);
            b10 = *(const f32x4*)(Bg1 + o);
            b11 = *(const f32x4*)(Bg1 + o + 4);
        }
        __builtin_amdgcn_sched_barrier(0);   // keep loads above the MFMA block

        const unsigned short* sA = lA[t & 1];
        const unsigned short* sB = lB[t & 1];
        short8 bf[8], af[4];
        #pragma unroll
        for (int ni = 0; ni < 8; ++ni) bf[ni] = *(const short8*)&sB[offB[ni]];
        #pragma unroll
        for (int mi = 0; mi < 4; ++mi) af[mi] = *(const short8*)&sA[offA[mi]];
        #pragma unroll
        for (int mi = 0; mi < 4; ++mi)
            #pragma unroll
            for (int ni = 0; ni < 8; ++ni)
                acc[mi][ni] = __builtin_amdgcn_mfma_f32_16x16x32_bf16(
                    af[mi], bf[ni], acc[mi][ni], 0, 0, 0);

        if (t + 1 < KITERS) {   // cvt + write next tile into the other buffer
            const int nb2 = (t + 1) & 1;
            *(short8*)&lA[nb2][wA]  = pack8(a0, a1);
            *(short8*)&lB[nb2][wB0] = pack8(b00, b01);
            *(short8*)&lB[nb2][wB1] = pack8(b10, b11);
        }
        __syncthreads();
    }

    // ---- epilogue. C/D 16x16x32: col = lane&15, row = (lane>>4)*4 + j.
    if (USE_WS) {
        // permuted-column slice: within each 128-col wave region, store the 8
        // ni-values of one lane contiguously: colp = wn + L*8 + ni  (L = lane&15).
        // reduce kernel inverts: col = 128*c128 + ni*16 + L.
        unsigned short* slice = wsb + (size_t)kb * SLICE_ELEMS;
        const int colp = bn + wn + fr * 8;
        #pragma unroll
        for (int mi = 0; mi < 4; ++mi) {
            #pragma unroll
            for (int j = 0; j < 4; ++j) {
                const int r = wm + mi * 16 + q * 4 + j;
                short8 v;
                #pragma unroll
                for (int ni = 0; ni < 8; ++ni) v[ni] = f2bf(acc[mi][ni][j]);
                *(short8*)&slice[(size_t)r * CO + colp] = v;
            }
        }
    } else {
        #pragma unroll
        for (int mi = 0; mi < 4; ++mi)
            #pragma unroll
            for (int ni = 0; ni < 8; ++ni) {
                const int col = bn + wn + ni * 16 + fr;
                #pragma unroll
                for (int j = 0; j < 4; ++j) {
                    const int r = wm + mi * 16 + q * 4 + j;
                    unsafeAtomicAdd(out + (size_t)r * CO + col, acc[mi][ni][j]);
                }
            }
    }
}

// sum SKB bf16 slices elementwise, then invert the column permutation.
__global__ __launch_bounds__(256)
void reduce_splitk_v5(const unsigned short* __restrict__ ws, float* __restrict__ out) {
    const int g = blockIdx.x * 256 + threadIdx.x;       // short8 group, 0..32767
    const short8* base = (const short8*)ws;
    float s[8] = {0, 0, 0, 0, 0, 0, 0, 0};
    #pragma unroll 8
    for (int sdx = 0; sdx < SKB; ++sdx) {
        short8 v = base[(size_t)sdx * (SLICE_ELEMS / 8) + g];
        #pragma unroll
        for (int e = 0; e < 8; ++e) {
            unsigned int u = ((unsigned int)(unsigned short)v[e]) << 16;
            s[e] += __builtin_bit_cast(float, u);
        }
    }
    const int r    = g >> 7;                 // output row (b)
    const int rem  = g & 127;
    const int c128 = rem >> 4;               // 128-col region
    const int L    = rem & 15;
    float* orow = out + (size_t)r * CO + c128 * 128 + L;
    #pragma unroll
    for (int e = 0; e < 8; ++e) orow[e * 16] = s[e];
}

extern "C" void kernel_launch(void* const* d_in, const int* in_sizes, int n_in,
                              void* d_out, int out_size, void* d_ws, size_t ws_size,
                              hipStream_t stream) {
    const float* A = (const float*)d_in[0];
    const float* W = (const float*)d_in[1];
    float* out = (float*)d_out;
    unsigned short* ws = (unsigned short*)d_ws;

    const size_t ws_needed = (size_t)SKB * SLICE_ELEMS * sizeof(unsigned short); // 32 MB
    dim3 grid(NB, SKB);   // 2 x 64 = 128 blocks, 1024 threads each

    if (ws_size >= ws_needed) {
        sconv_gemm_v5<true><<<grid, 1024, 0, stream>>>(A, W, out, ws);
        reduce_splitk_v5<<<SLICE_ELEMS / 8 / 256, 256, 0, stream>>>(ws, out);
    } else {
        hipMemsetAsync(d_out, 0, (size_t)out_size * sizeof(float), stream);
        sconv_gemm_v5<false><<<grid, 1024, 0, stream>>>(A, W, out, ws);
    }
}

// Round 6
// 29.658 us; speedup vs baseline: 6.2914x; 6.2914x over previous
//
#include <hip/hip_runtime.h>
#include <hip/hip_bf16.h>

// StreamingConv == GEMM: C[b,o] = sum_k A[b,k]*W[o,k]; A[256][16384], W[1024][16384] f32.
// R6: R4 structure (global_load_lds + counted vmcnt, f32-in-LDS XOR-swizzled, 512 thr,
// 2 waves/SIMD -> 256-reg budget, no spill). Traffic cuts vs R4 (199 MB -> ~116 MB):
//  - XCD co-scheduling: all 8 n-blocks sharing an A k-chunk get wgid === kb (mod 8)
//    -> same XCD -> A fetched once into that L2 (A: 67 -> 16.8 MB logical).
//  - SKB=32 (KC=512): ws 64 -> 32 MB round trip.
//  - BN=128: acc = 64 f32/thread. Permuted short4 epilogue; reduce inverts the perm.

#define CO    1024
#define KTOT  16384
#define BM    256
#define BN    128
#define NB    8                    // n-blocks
#define SKB   32                   // split-K blocks
#define KC    (KTOT / SKB)         // 512
#define BK    32                   // f32 k-step in LDS; row = 128 B = 8 x 16B groups
#define KITERS (KC / BK)           // 16
#define SLICE_ELEMS (BM * CO)      // 262144 bf16 per slice

typedef __attribute__((ext_vector_type(8))) short short8;
typedef __attribute__((ext_vector_type(4))) float f32x4;
typedef __attribute__((ext_vector_type(4))) unsigned short u16x4;

__device__ __forceinline__ unsigned short f2bf(float f) {
    union { __bf16 h; unsigned short u; } c; c.h = (__bf16)f; return c.u;
}

__device__ __forceinline__ void gl_lds16(const float* g, const float* lds_uniform) {
    __builtin_amdgcn_global_load_lds(
        (const __attribute__((address_space(1))) void*)g,
        (__attribute__((address_space(3))) void*)lds_uniform, 16, 0, 0);
}

template <bool USE_WS>
__global__ __launch_bounds__(512, 2)
void sconv_gemm_v6(const float* __restrict__ A, const float* __restrict__ W,
                   float* __restrict__ out, unsigned short* __restrict__ wsb) {
    // f32 tiles, XOR-swizzled: physical 16B-group = logical_group ^ (row & 7)
    __shared__ float lA[2][BM * BK];    // 2 x 32 KB
    __shared__ float lB[2][BN * BK];    // 2 x 16 KB

    const int tid  = threadIdx.x;
    const int wid  = tid >> 6;
    const int lane = tid & 63;

    // decode (kb, nb) from wgid so that wgid % 8 == kb % 8  (same-A blocks -> same XCD)
    const int wgid = blockIdx.x;
    const int c  = wgid & 7;
    const int rs = wgid >> 3;
    const int nb = rs & 7;
    const int kb = (rs >> 3) * 8 + c;     // 0..31
    const int bn = nb * BN;
    const int k0 = kb * KC;

    // ---- staging decomposition ----
    // A tile: 256 rows x 8 groups = 2048 16B-slots, 4/thread; B: 128x8 = 1024, 2/thread.
    // slot s -> row = s>>3, phys group = s&7, source k-group = (s&7) ^ (row&7)
    const float* Asrc = A + k0;
    const float* Wsrc = W + (size_t)bn * KTOT + k0;

    int aRow[4], aGk[4], aLds[4];
    #pragma unroll
    for (int j = 0; j < 4; ++j) {
        int s = j * 512 + tid;
        aRow[j] = s >> 3;
        aGk[j]  = (s & 7) ^ (aRow[j] & 7);
        aLds[j] = (j * 512 + wid * 64) * 4;       // wave-uniform base (floats)
    }
    int bRow[2], bGk[2], bLds[2];
    #pragma unroll
    for (int j = 0; j < 2; ++j) {
        int s = j * 512 + tid;
        bRow[j] = s >> 3;
        bGk[j]  = (s & 7) ^ (bRow[j] & 7);
        bLds[j] = (j * 512 + wid * 64) * 4;
    }

#define STAGE(BUF, T) {                                                          \
        _Pragma("unroll")                                                        \
        for (int j = 0; j < 4; ++j)                                              \
            gl_lds16(Asrc + (size_t)aRow[j] * KTOT + (T) * BK + aGk[j] * 4,      \
                     &lA[BUF][aLds[j]]);                                         \
        _Pragma("unroll")                                                        \
        for (int j = 0; j < 2; ++j)                                              \
            gl_lds16(Wsrc + (size_t)bRow[j] * KTOT + (T) * BK + bGk[j] * 4,      \
                     &lB[BUF][bLds[j]]);                                         \
    }
    // 6 gl_lds per thread per STAGE -> vmcnt(6) after issuing next STAGE means
    // "previous STAGE fully landed".

    // ---- wave -> 64M x 64N sub-tile (4x2 wave grid over 256x128) ----
    const int wm = (wid >> 1) * 64;
    const int wn = (wid & 1) * 64;
    const int q  = lane >> 4;            // k-quarter: lane k-start = q*8
    const int fr = lane & 15;

    f32x4 acc[4][4] = {};

#define COMPUTE(BUF) {                                                           \
        short8 bf[4];                                                            \
        _Pragma("unroll")                                                        \
        for (int ni = 0; ni < 4; ++ni) {                                         \
            int r = wn + ni * 16 + fr;                                           \
            int sw = r & 7;                                                      \
            f32x4 v0 = *(const f32x4*)&lB[BUF][r * BK + (((q*2)     ^ sw) * 4)]; \
            f32x4 v1 = *(const f32x4*)&lB[BUF][r * BK + (((q*2 + 1) ^ sw) * 4)]; \
            short8 tb;                                                           \
            tb[0]=f2bf(v0[0]); tb[1]=f2bf(v0[1]); tb[2]=f2bf(v0[2]); tb[3]=f2bf(v0[3]); \
            tb[4]=f2bf(v1[0]); tb[5]=f2bf(v1[1]); tb[6]=f2bf(v1[2]); tb[7]=f2bf(v1[3]); \
            bf[ni] = tb;                                                         \
        }                                                                        \
        _Pragma("unroll")                                                        \
        for (int mi = 0; mi < 4; ++mi) {                                         \
            int r = wm + mi * 16 + fr;                                           \
            int sw = r & 7;                                                      \
            f32x4 v0 = *(const f32x4*)&lA[BUF][r * BK + (((q*2)     ^ sw) * 4)]; \
            f32x4 v1 = *(const f32x4*)&lA[BUF][r * BK + (((q*2 + 1) ^ sw) * 4)]; \
            short8 af;                                                           \
            af[0]=f2bf(v0[0]); af[1]=f2bf(v0[1]); af[2]=f2bf(v0[2]); af[3]=f2bf(v0[3]); \
            af[4]=f2bf(v1[0]); af[5]=f2bf(v1[1]); af[6]=f2bf(v1[2]); af[7]=f2bf(v1[3]); \
            _Pragma("unroll")                                                    \
            for (int ni = 0; ni < 4; ++ni)                                       \
                acc[mi][ni] = __builtin_amdgcn_mfma_f32_16x16x32_bf16(           \
                    af, bf[ni], acc[mi][ni], 0, 0, 0);                           \
        }                                                                        \
    }

    STAGE(0, 0);
    #pragma unroll
    for (int t = 0; t < KITERS; ++t) {
        const int buf = t & 1;
        asm volatile("" ::: "memory");
        __builtin_amdgcn_s_barrier();            // everyone done READING buf (prev round)
        asm volatile("" ::: "memory");
        if (t + 1 < KITERS) {
            STAGE(buf ^ 1, t + 1);
            asm volatile("s_waitcnt vmcnt(6)" ::: "memory");   // buf's 6 loads landed
        } else {
            asm volatile("s_waitcnt vmcnt(0)" ::: "memory");
        }
        __builtin_amdgcn_s_barrier();            // all waves' buf data visible
        asm volatile("" ::: "memory");
        COMPUTE(buf);
    }
#undef STAGE
#undef COMPUTE

    // ---- epilogue. C/D 16x16x32: col = lane&15 (=fr), row = q*4 + j.
    if (USE_WS) {
        // permuted columns within each 64-col wave region: colp = fr*4 + ni
        // (true col = ni*16 + fr); reduce kernel inverts.
        unsigned short* slice = wsb + (size_t)kb * SLICE_ELEMS;
        const int pbase = bn + wn + fr * 4;
        #pragma unroll
        for (int mi = 0; mi < 4; ++mi) {
            #pragma unroll
            for (int j = 0; j < 4; ++j) {
                const int r = wm + mi * 16 + q * 4 + j;
                u16x4 v;
                #pragma unroll
                for (int ni = 0; ni < 4; ++ni) v[ni] = f2bf(acc[mi][ni][j]);
                *(u16x4*)&slice[(size_t)r * CO + pbase] = v;
            }
        }
    } else {
        #pragma unroll
        for (int mi = 0; mi < 4; ++mi)
            #pragma unroll
            for (int ni = 0; ni < 4; ++ni) {
                const int col = bn + wn + ni * 16 + fr;
                #pragma unroll
                for (int j = 0; j < 4; ++j) {
                    const int r = wm + mi * 16 + q * 4 + j;
                    unsafeAtomicAdd(out + (size_t)r * CO + col, acc[mi][ni][j]);
                }
            }
    }
}

// sum 32 bf16 slices elementwise and invert the column permutation.
// group g (u16x4 unit): r = g>>8, p = g&255, c64 = p>>4, L = p&15;
// element e -> out col = c64*64 + e*16 + L.
__global__ __launch_bounds__(256)
void reduce_splitk_v6(const unsigned short* __restrict__ ws, float* __restrict__ out) {
    const int g = blockIdx.x * 256 + threadIdx.x;    // 0 .. 65535
    const u16x4* base = (const u16x4*)ws;
    float s[4] = {0, 0, 0, 0};
    #pragma unroll 8
    for (int sdx = 0; sdx < SKB; ++sdx) {
        u16x4 v = base[(size_t)sdx * (SLICE_ELEMS / 4) + g];
        #pragma unroll
        for (int e = 0; e < 4; ++e) {
            unsigned int u = ((unsigned int)v[e]) << 16;
            s[e] += __builtin_bit_cast(float, u);
        }
    }
    const int r   = g >> 8;
    const int p   = g & 255;
    const int c64 = p >> 4;
    const int L   = p & 15;
    float* orow = out + (size_t)r * CO + c64 * 64 + L;
    #pragma unroll
    for (int e = 0; e < 4; ++e) orow[e * 16] = s[e];
}

extern "C" void kernel_launch(void* const* d_in, const int* in_sizes, int n_in,
                              void* d_out, int out_size, void* d_ws, size_t ws_size,
                              hipStream_t stream) {
    const float* A = (const float*)d_in[0];
    const float* W = (const float*)d_in[1];
    float* out = (float*)d_out;
    unsigned short* ws = (unsigned short*)d_ws;

    const size_t ws_needed = (size_t)SKB * SLICE_ELEMS * sizeof(unsigned short); // 16 MB

    if (ws_size >= ws_needed) {
        sconv_gemm_v6<true><<<NB * SKB, 512, 0, stream>>>(A, W, out, ws);
        reduce_splitk_v6<<<SLICE_ELEMS / 4 / 256, 256, 0, stream>>>(ws, out);
    } else {
        hipMemsetAsync(d_out, 0, (size_t)out_size * sizeof(float), stream);
        sconv_gemm_v6<false><<<NB * SKB, 512, 0, stream>>>(A, W, out, ws);
    }
}